// Round 9
// baseline (347.392 us; speedup 1.0000x reference)
//
#include <hip/hip_runtime.h>
#include <hip/hip_bf16.h>

// ---------------------------------------------------------------------------
// GraphSAGE (3x SAGEConv mean + linear head), CSR gather formulation.
// R9: neighbor-mean gather FUSED into the MFMA GEMMs — each MFMA lane
// accumulates exactly its own A-fragment slices over the neighbor list
// (agg buffer round-trips and 3 aggregate launches eliminated);
// setup kernels merged. 8 dispatches total.
// ---------------------------------------------------------------------------

#define SCAN_CHUNK 2048

typedef unsigned short bf16_t;
typedef unsigned int uint32;
typedef __attribute__((ext_vector_type(8))) short bf16x8;   // 8 bf16 = 4 VGPRs
typedef __attribute__((ext_vector_type(4))) float f32x4;

__device__ __forceinline__ bf16_t f2bf(float f) {
    uint32 u = __float_as_uint(f);
    u += 0x7fff + ((u >> 16) & 1);           // round-to-nearest-even
    return (bf16_t)(u >> 16);
}
__device__ __forceinline__ float bf2f(bf16_t b) {
    return __uint_as_float((uint32)b << 16);
}
__device__ __forceinline__ void acc8(float* acc, uint4 v) {
    acc[0] += bf2f((bf16_t)(v.x & 0xffff)); acc[1] += bf2f((bf16_t)(v.x >> 16));
    acc[2] += bf2f((bf16_t)(v.y & 0xffff)); acc[3] += bf2f((bf16_t)(v.y >> 16));
    acc[4] += bf2f((bf16_t)(v.z & 0xffff)); acc[5] += bf2f((bf16_t)(v.z >> 16));
    acc[6] += bf2f((bf16_t)(v.w & 0xffff)); acc[7] += bf2f((bf16_t)(v.w >> 16));
}

// ---- setup: zero deg + convert all three weight matrices to bf16 ----------
// grid = nZero + 16 + 128 + 128 blocks
__global__ __launch_bounds__(256) void prep_kernel(
    int* __restrict__ deg, int N,
    const float* __restrict__ Wl1, const float* __restrict__ Wr1, bf16_t* __restrict__ w1,
    const float* __restrict__ Wl2, const float* __restrict__ Wr2, bf16_t* __restrict__ w2,
    const float* __restrict__ Wl3, const float* __restrict__ Wr3, bf16_t* __restrict__ w3) {
    const int nZero = (N + 255) >> 8;
    const int b = blockIdx.x;
    const int t = threadIdx.x;
    if (b < nZero) {
        int i = b * 256 + t;
        if (i < N) deg[i] = 0;
    } else if (b < nZero + 16) {
        int idx = (b - nZero) * 256 + t;         // 0..4095
        int o = idx >> 5, k = idx & 31;
        float v = (k < 16) ? Wl1[o * 16 + k] : Wr1[o * 16 + k - 16];
        w1[idx] = f2bf(v);
    } else if (b < nZero + 144) {
        int idx = (b - nZero - 16) * 256 + t;    // 0..32767
        int o = idx >> 8, k = idx & 255;
        float v = (k < 128) ? Wl2[o * 128 + k] : Wr2[o * 128 + k - 128];
        w2[idx] = f2bf(v);
    } else {
        int idx = (b - nZero - 144) * 256 + t;
        int o = idx >> 8, k = idx & 255;
        float v = (k < 128) ? Wl3[o * 128 + k] : Wr3[o * 128 + k - 128];
        w3[idx] = f2bf(v);
    }
}

__global__ void count_deg_kernel(const int* __restrict__ dst, int* __restrict__ deg, int E) {
    int e = blockIdx.x * 256 + threadIdx.x;
    if (e < E) atomicAdd(&deg[dst[e]], 1);
}

__global__ __launch_bounds__(256) void scan_partial_kernel(
    const int* __restrict__ deg, int* __restrict__ blocksum, int N) {
    __shared__ int s[256];
    const int t = threadIdx.x;
    const int base = blockIdx.x * SCAN_CHUNK + t * 8;
    int sum = 0;
    #pragma unroll
    for (int j = 0; j < 8; ++j) {
        int i = base + j;
        if (i < N) sum += deg[i];
    }
    s[t] = sum;
    __syncthreads();
    #pragma unroll
    for (int off = 128; off > 0; off >>= 1) {
        if (t < off) s[t] += s[t + off];
        __syncthreads();
    }
    if (t == 0) blocksum[blockIdx.x] = s[0];
}

__global__ __launch_bounds__(256) void scan_final_kernel(
    const int* __restrict__ deg, const int* __restrict__ blocksum,
    int* __restrict__ rowptr, int* __restrict__ cursor,
    float* __restrict__ inv, int N) {
    __shared__ int s[256];
    __shared__ int blockoff_s;
    const int t = threadIdx.x;
    if (t == 0) {
        int off = 0;
        for (int b = 0; b < (int)blockIdx.x; ++b) off += blocksum[b];
        blockoff_s = off;
    }
    const int base = blockIdx.x * SCAN_CHUNK + t * 8;
    int v[8];
    int sum = 0;
    #pragma unroll
    for (int j = 0; j < 8; ++j) {
        int i = base + j;
        v[j] = (i < N) ? deg[i] : 0;
        sum += v[j];
    }
    s[t] = sum;
    __syncthreads();
    for (int off = 1; off < 256; off <<= 1) {
        int val = (t >= off) ? s[t - off] : 0;
        __syncthreads();
        s[t] += val;
        __syncthreads();
    }
    int run = blockoff_s + ((t == 0) ? 0 : s[t - 1]);
    #pragma unroll
    for (int j = 0; j < 8; ++j) {
        int i = base + j;
        if (i < N) {
            rowptr[i] = run;
            cursor[i] = run;
            inv[i] = 1.0f / (float)max(v[j], 1);
            run += v[j];
        }
    }
    if ((int)blockIdx.x == (int)gridDim.x - 1 && t == 255) rowptr[N] = run;
}

__global__ void fill_csr_kernel(const int* __restrict__ src, const int* __restrict__ dst,
                                int* __restrict__ cursor, int* __restrict__ col, int E) {
    int e = blockIdx.x * 256 + threadIdx.x;
    if (e >= E) return;
    int pos = atomicAdd(&cursor[dst[e]], 1);
    col[pos] = src[e];
}

// ---- layer 1 fused: gather x-mean + MFMA (K=32) --------------------------
// A-frag lane (r,q): k=q*8..+7; k<16 -> mean slice, k>=16 -> own x slice.
__global__ __launch_bounds__(256) void layer16_fused_kernel(
    const float* __restrict__ x, const int* __restrict__ rowptr,
    const int* __restrict__ col, const float* __restrict__ inv,
    const bf16_t* __restrict__ wbf1, const float* __restrict__ bias,
    bf16_t* __restrict__ hout, int n) {
    const int t = threadIdx.x;
    const int lane = t & 63;
    const int wave = t >> 6;
    const int r = lane & 15;
    const int q = lane >> 4;
    const int m0 = blockIdx.x * 64 + (wave >> 1) * 32;
    const int nb = (wave & 1) * 64;

    bf16x8 aF[2];
    #pragma unroll
    for (int mt = 0; mt < 2; ++mt) {
        int node = m0 + mt * 16 + r;
        if (node >= n) node = n - 1;
        float acc[8];
        if (q < 2) {
            // gather mean of x feats q*8..+7
            #pragma unroll
            for (int j = 0; j < 8; ++j) acc[j] = 0.f;
            const int lo = rowptr[node], hi = rowptr[node + 1];
            int e = lo;
            for (; e + 1 < hi; e += 2) {
                int s0 = col[e], s1 = col[e + 1];
                float4 u0 = *(const float4*)&x[s0 * 16 + q * 8];
                float4 u1 = *(const float4*)&x[s0 * 16 + q * 8 + 4];
                float4 u2 = *(const float4*)&x[s1 * 16 + q * 8];
                float4 u3 = *(const float4*)&x[s1 * 16 + q * 8 + 4];
                acc[0] += u0.x + u2.x; acc[1] += u0.y + u2.y;
                acc[2] += u0.z + u2.z; acc[3] += u0.w + u2.w;
                acc[4] += u1.x + u3.x; acc[5] += u1.y + u3.y;
                acc[6] += u1.z + u3.z; acc[7] += u1.w + u3.w;
            }
            if (e < hi) {
                int s0 = col[e];
                float4 u0 = *(const float4*)&x[s0 * 16 + q * 8];
                float4 u1 = *(const float4*)&x[s0 * 16 + q * 8 + 4];
                acc[0] += u0.x; acc[1] += u0.y; acc[2] += u0.z; acc[3] += u0.w;
                acc[4] += u1.x; acc[5] += u1.y; acc[6] += u1.z; acc[7] += u1.w;
            }
            float iv = inv[node];
            #pragma unroll
            for (int j = 0; j < 8; ++j) acc[j] *= iv;
        } else {
            float4 u0 = *(const float4*)&x[node * 16 + (q - 2) * 8];
            float4 u1 = *(const float4*)&x[node * 16 + (q - 2) * 8 + 4];
            acc[0] = u0.x; acc[1] = u0.y; acc[2] = u0.z; acc[3] = u0.w;
            acc[4] = u1.x; acc[5] = u1.y; acc[6] = u1.z; acc[7] = u1.w;
        }
        #pragma unroll
        for (int j = 0; j < 8; ++j) aF[mt][j] = (short)f2bf(acc[j]);
    }

    #pragma unroll
    for (int nt = 0; nt < 4; ++nt) {
        const int cidx = nb + nt * 16 + r;
        bf16x8 bF = *(const bf16x8*)(wbf1 + (size_t)cidx * 32 + q * 8);
        f32x4 acc0 = {0.f, 0.f, 0.f, 0.f};
        f32x4 acc1 = {0.f, 0.f, 0.f, 0.f};
        acc0 = __builtin_amdgcn_mfma_f32_16x16x32_bf16(aF[0], bF, acc0, 0, 0, 0);
        acc1 = __builtin_amdgcn_mfma_f32_16x16x32_bf16(aF[1], bF, acc1, 0, 0, 0);
        float bo = bias[cidx];
        #pragma unroll
        for (int reg = 0; reg < 4; ++reg) {
            int row0 = m0 + q * 4 + reg;
            if (row0 < n)
                hout[(size_t)row0 * 128 + cidx] = f2bf(fmaxf(acc0[reg] + bo, 0.0f));
            int row1 = m0 + 16 + q * 4 + reg;
            if (row1 < n)
                hout[(size_t)row1 * 128 + cidx] = f2bf(fmaxf(acc1[reg] + bo, 0.0f));
        }
    }
}

// ---- layers 2/3 fused: per-lane neighbor gather -> A-frag -> MFMA --------
// Lane (r,q) accumulates agg slices {ks*32+q*8..+7, ks=0..3} of its node.
template <bool FUSE_HEAD>
__device__ __forceinline__ void layer128_fused_body(
    const bf16_t* __restrict__ hin, const int* __restrict__ rowptr,
    const int* __restrict__ col, const float* __restrict__ inv,
    const bf16_t* __restrict__ wbf, const float* __restrict__ bias,
    const float* __restrict__ Wh, const float* __restrict__ bh,
    bf16_t* __restrict__ hout, float* __restrict__ out, int n) {
    __shared__ bf16_t hs[FUSE_HEAD ? 64 : 1][FUSE_HEAD ? 132 : 1];

    const int t = threadIdx.x;
    const int lane = t & 63;
    const int wave = t >> 6;
    const int r = lane & 15;
    const int q = lane >> 4;
    const int n0 = blockIdx.x * 64;
    const int m0 = n0 + (wave >> 1) * 32;
    const int nb = (wave & 1) * 64;

    bf16x8 aF[2][8];
    #pragma unroll
    for (int mt = 0; mt < 2; ++mt) {
        int node = m0 + mt * 16 + r;
        if (node >= n) node = n - 1;
        // gather mean: 32 feats (4 slices of 8) of this node's neighbors
        float acc[32];
        #pragma unroll
        for (int j = 0; j < 32; ++j) acc[j] = 0.f;
        const int lo = rowptr[node], hi = rowptr[node + 1];
        int e = lo;
        for (; e + 1 < hi; e += 2) {
            const bf16_t* r0 = hin + (size_t)col[e] * 128 + q * 8;
            const bf16_t* r1 = hin + (size_t)col[e + 1] * 128 + q * 8;
            #pragma unroll
            for (int ks = 0; ks < 4; ++ks) {
                uint4 v0 = *(const uint4*)(r0 + ks * 32);
                uint4 v1 = *(const uint4*)(r1 + ks * 32);
                acc8(&acc[ks * 8], v0);
                acc8(&acc[ks * 8], v1);
            }
        }
        if (e < hi) {
            const bf16_t* r0 = hin + (size_t)col[e] * 128 + q * 8;
            #pragma unroll
            for (int ks = 0; ks < 4; ++ks) {
                uint4 v0 = *(const uint4*)(r0 + ks * 32);
                acc8(&acc[ks * 8], v0);
            }
        }
        const float iv = inv[node];
        #pragma unroll
        for (int ks = 0; ks < 4; ++ks)
            #pragma unroll
            for (int j = 0; j < 8; ++j)
                aF[mt][ks][j] = (short)f2bf(acc[ks * 8 + j] * iv);
        // self h slices straight from global
        const bf16_t* hrow = hin + (size_t)node * 128;
        #pragma unroll
        for (int ks = 0; ks < 4; ++ks)
            aF[mt][4 + ks] = *(const bf16x8*)(hrow + ks * 32 + q * 8);
    }

    const int mloc = (wave >> 1) * 32;
    #pragma unroll
    for (int nt = 0; nt < 4; ++nt) {
        const int cidx = nb + nt * 16 + r;
        const bf16_t* wrow = wbf + (size_t)cidx * 256;
        f32x4 acc0 = {0.f, 0.f, 0.f, 0.f};
        f32x4 acc1 = {0.f, 0.f, 0.f, 0.f};
        #pragma unroll
        for (int ks = 0; ks < 8; ++ks) {
            bf16x8 bF = *(const bf16x8*)(wrow + ks * 32 + q * 8);
            acc0 = __builtin_amdgcn_mfma_f32_16x16x32_bf16(aF[0][ks], bF, acc0, 0, 0, 0);
            acc1 = __builtin_amdgcn_mfma_f32_16x16x32_bf16(aF[1][ks], bF, acc1, 0, 0, 0);
        }
        float bo = bias[cidx];
        #pragma unroll
        for (int reg = 0; reg < 4; ++reg) {
            if (FUSE_HEAD) {
                hs[mloc + q * 4 + reg][cidx]      = f2bf(fmaxf(acc0[reg] + bo, 0.0f));
                hs[mloc + 16 + q * 4 + reg][cidx] = f2bf(fmaxf(acc1[reg] + bo, 0.0f));
            } else {
                int row0 = m0 + q * 4 + reg;
                if (row0 < n)
                    hout[(size_t)row0 * 128 + cidx] = f2bf(fmaxf(acc0[reg] + bo, 0.0f));
                int row1 = m0 + 16 + q * 4 + reg;
                if (row1 < n)
                    hout[(size_t)row1 * 128 + cidx] = f2bf(fmaxf(acc1[reg] + bo, 0.0f));
            }
        }
    }

    if (FUSE_HEAD) {
        __syncthreads();
        const int nl = t >> 2;
        const int o  = t & 3;
        const int node = n0 + nl;
        if (node >= n) return;
        const float* wr = Wh + o * 128;
        float acc = bh[o];
        #pragma unroll
        for (int kb = 0; kb < 16; ++kb) {
            bf16x8 hv = *(const bf16x8*)&hs[nl][kb * 8];
            float4 w0 = *(const float4*)&wr[kb * 8];
            float4 w1 = *(const float4*)&wr[kb * 8 + 4];
            acc = fmaf(bf2f((bf16_t)hv[0]), w0.x, acc);
            acc = fmaf(bf2f((bf16_t)hv[1]), w0.y, acc);
            acc = fmaf(bf2f((bf16_t)hv[2]), w0.z, acc);
            acc = fmaf(bf2f((bf16_t)hv[3]), w0.w, acc);
            acc = fmaf(bf2f((bf16_t)hv[4]), w1.x, acc);
            acc = fmaf(bf2f((bf16_t)hv[5]), w1.y, acc);
            acc = fmaf(bf2f((bf16_t)hv[6]), w1.z, acc);
            acc = fmaf(bf2f((bf16_t)hv[7]), w1.w, acc);
        }
        out[(size_t)node * 4 + o] = acc;
    }
}

__global__ __launch_bounds__(256) void layer128_fused_kernel(
    const bf16_t* __restrict__ hin, const int* __restrict__ rowptr,
    const int* __restrict__ col, const float* __restrict__ inv,
    const bf16_t* __restrict__ wbf, const float* __restrict__ bias,
    bf16_t* __restrict__ hout, int n) {
    layer128_fused_body<false>(hin, rowptr, col, inv, wbf, bias,
                               nullptr, nullptr, hout, nullptr, n);
}

__global__ __launch_bounds__(256) void layer128_head_fused_kernel(
    const bf16_t* __restrict__ hin, const int* __restrict__ rowptr,
    const int* __restrict__ col, const float* __restrict__ inv,
    const bf16_t* __restrict__ wbf, const float* __restrict__ bias,
    const float* __restrict__ Wh, const float* __restrict__ bh,
    float* __restrict__ out, int n) {
    layer128_fused_body<true>(hin, rowptr, col, inv, wbf, bias,
                              Wh, bh, nullptr, out, n);
}

extern "C" void kernel_launch(void* const* d_in, const int* in_sizes, int n_in,
                              void* d_out, int out_size, void* d_ws, size_t ws_size,
                              hipStream_t stream) {
    const float* x   = (const float*)d_in[0];
    const int*   ei  = (const int*)d_in[1];
    const float* Wl1 = (const float*)d_in[2];
    const float* Wr1 = (const float*)d_in[3];
    const float* b1  = (const float*)d_in[4];
    const float* Wl2 = (const float*)d_in[5];
    const float* Wr2 = (const float*)d_in[6];
    const float* b2  = (const float*)d_in[7];
    const float* Wl3 = (const float*)d_in[8];
    const float* Wr3 = (const float*)d_in[9];
    const float* b3  = (const float*)d_in[10];
    const float* Wh  = (const float*)d_in[11];
    const float* bh  = (const float*)d_in[12];
    float* out = (float*)d_out;

    const int N = in_sizes[0] / 16;
    const int E = in_sizes[1] / 2;
    const int* src = ei;
    const int* dst = ei + E;

    const int nScanBlocks = (N + SCAN_CHUNK - 1) / SCAN_CHUNK;
    const int nZero = (N + 255) >> 8;

    int* deg       = (int*)d_ws;                       // N
    int* rowptr    = deg + N;                          // N+1 (pad 8)
    int* cursor    = rowptr + (N + 8);                 // N
    int* blocksum  = cursor + N;                       // pad 64
    int* col       = blocksum + 64;                    // E
    float* inv     = (float*)(col + E);                // N
    bf16_t* hA     = (bf16_t*)(inv + N);               // N*128 bf16
    bf16_t* hB     = hA + (size_t)N * 128;             // N*128 bf16
    bf16_t* wbf1   = hB + (size_t)N * 128;             // 128*32 bf16
    bf16_t* wbf2   = wbf1 + 128 * 32;                  // 128*256 bf16
    bf16_t* wbf3   = wbf2 + 128 * 256;                 // 128*256 bf16

    const int B = 256;
    auto blocks = [](long total, int b) { return (int)((total + b - 1) / b); };

    // ---- setup + CSR build (5 dispatches) ----
    prep_kernel<<<nZero + 272, B, 0, stream>>>(deg, N, Wl1, Wr1, wbf1,
                                               Wl2, Wr2, wbf2, Wl3, Wr3, wbf3);
    count_deg_kernel<<<blocks(E, B), B, 0, stream>>>(dst, deg, E);
    scan_partial_kernel<<<nScanBlocks, B, 0, stream>>>(deg, blocksum, N);
    scan_final_kernel<<<nScanBlocks, B, 0, stream>>>(deg, blocksum, rowptr, cursor, inv, N);
    fill_csr_kernel<<<blocks(E, B), B, 0, stream>>>(src, dst, cursor, col, E);

    // ---- 3 fused gather+GEMM layers (3 dispatches) ----
    layer16_fused_kernel<<<blocks(N, 64), B, 0, stream>>>(
        x, rowptr, col, inv, wbf1, b1, hA, N);
    layer128_fused_kernel<<<blocks(N, 64), B, 0, stream>>>(
        hA, rowptr, col, inv, wbf2, b2, hB, N);
    layer128_head_fused_kernel<<<blocks(N, 64), B, 0, stream>>>(
        hB, rowptr, col, inv, wbf3, b3, Wh, bh, out, N);
}

// Round 10
// 295.308 us; speedup vs baseline: 1.1764x; 1.1764x over previous
//
#include <hip/hip_runtime.h>
#include <hip/hip_bf16.h>

// ---------------------------------------------------------------------------
// GraphSAGE (3x SAGEConv mean + linear head), CSR gather formulation.
// R10 = best-of-R8/R9 hybrid:
//   - prep merged (zero deg + 3 weight converts)     [R9, kept]
//   - layer16 with fused x-gather (K=32 MFMA)        [R9, kept]
//   - layers 2/3: SEPARATE high-occupancy coalesced aggregate128 + lean
//     MFMA GEMM (head fused into layer 3's epilogue) [R8, restored]
// R9 lesson: fusing the random gather into the 84-VGPR GEMM dropped
// occupancy 66%->21% and broke row coalescing -> 0.9 TB/s, +48us. Gathers
// need their own high-occupancy kernel with one 256B wave-read per row.
// ---------------------------------------------------------------------------

#define SCAN_CHUNK 2048

typedef unsigned short bf16_t;
typedef unsigned int uint32;
typedef __attribute__((ext_vector_type(8))) short bf16x8;   // 8 bf16 = 4 VGPRs
typedef __attribute__((ext_vector_type(4))) float f32x4;

__device__ __forceinline__ bf16_t f2bf(float f) {
    uint32 u = __float_as_uint(f);
    u += 0x7fff + ((u >> 16) & 1);           // round-to-nearest-even
    return (bf16_t)(u >> 16);
}
__device__ __forceinline__ float bf2f(bf16_t b) {
    return __uint_as_float((uint32)b << 16);
}
__device__ __forceinline__ void acc8(float* acc, uint4 v) {
    acc[0] += bf2f((bf16_t)(v.x & 0xffff)); acc[1] += bf2f((bf16_t)(v.x >> 16));
    acc[2] += bf2f((bf16_t)(v.y & 0xffff)); acc[3] += bf2f((bf16_t)(v.y >> 16));
    acc[4] += bf2f((bf16_t)(v.z & 0xffff)); acc[5] += bf2f((bf16_t)(v.z >> 16));
    acc[6] += bf2f((bf16_t)(v.w & 0xffff)); acc[7] += bf2f((bf16_t)(v.w >> 16));
}

// ---- setup: zero deg + convert all three weight matrices to bf16 ----------
__global__ __launch_bounds__(256) void prep_kernel(
    int* __restrict__ deg, int N,
    const float* __restrict__ Wl1, const float* __restrict__ Wr1, bf16_t* __restrict__ w1,
    const float* __restrict__ Wl2, const float* __restrict__ Wr2, bf16_t* __restrict__ w2,
    const float* __restrict__ Wl3, const float* __restrict__ Wr3, bf16_t* __restrict__ w3) {
    const int nZero = (N + 255) >> 8;
    const int b = blockIdx.x;
    const int t = threadIdx.x;
    if (b < nZero) {
        int i = b * 256 + t;
        if (i < N) deg[i] = 0;
    } else if (b < nZero + 16) {
        int idx = (b - nZero) * 256 + t;         // 0..4095
        int o = idx >> 5, k = idx & 31;
        float v = (k < 16) ? Wl1[o * 16 + k] : Wr1[o * 16 + k - 16];
        w1[idx] = f2bf(v);
    } else if (b < nZero + 144) {
        int idx = (b - nZero - 16) * 256 + t;    // 0..32767
        int o = idx >> 8, k = idx & 255;
        float v = (k < 128) ? Wl2[o * 128 + k] : Wr2[o * 128 + k - 128];
        w2[idx] = f2bf(v);
    } else {
        int idx = (b - nZero - 144) * 256 + t;
        int o = idx >> 8, k = idx & 255;
        float v = (k < 128) ? Wl3[o * 128 + k] : Wr3[o * 128 + k - 128];
        w3[idx] = f2bf(v);
    }
}

__global__ void count_deg_kernel(const int* __restrict__ dst, int* __restrict__ deg, int E) {
    int e = blockIdx.x * 256 + threadIdx.x;
    if (e < E) atomicAdd(&deg[dst[e]], 1);
}

__global__ __launch_bounds__(256) void scan_partial_kernel(
    const int* __restrict__ deg, int* __restrict__ blocksum, int N) {
    __shared__ int s[256];
    const int t = threadIdx.x;
    const int base = blockIdx.x * SCAN_CHUNK + t * 8;
    int sum = 0;
    #pragma unroll
    for (int j = 0; j < 8; ++j) {
        int i = base + j;
        if (i < N) sum += deg[i];
    }
    s[t] = sum;
    __syncthreads();
    #pragma unroll
    for (int off = 128; off > 0; off >>= 1) {
        if (t < off) s[t] += s[t + off];
        __syncthreads();
    }
    if (t == 0) blocksum[blockIdx.x] = s[0];
}

__global__ __launch_bounds__(256) void scan_final_kernel(
    const int* __restrict__ deg, const int* __restrict__ blocksum,
    int* __restrict__ rowptr, int* __restrict__ cursor,
    float* __restrict__ inv, int N) {
    __shared__ int s[256];
    __shared__ int blockoff_s;
    const int t = threadIdx.x;
    if (t == 0) {
        int off = 0;
        for (int b = 0; b < (int)blockIdx.x; ++b) off += blocksum[b];
        blockoff_s = off;
    }
    const int base = blockIdx.x * SCAN_CHUNK + t * 8;
    int v[8];
    int sum = 0;
    #pragma unroll
    for (int j = 0; j < 8; ++j) {
        int i = base + j;
        v[j] = (i < N) ? deg[i] : 0;
        sum += v[j];
    }
    s[t] = sum;
    __syncthreads();
    for (int off = 1; off < 256; off <<= 1) {
        int val = (t >= off) ? s[t - off] : 0;
        __syncthreads();
        s[t] += val;
        __syncthreads();
    }
    int run = blockoff_s + ((t == 0) ? 0 : s[t - 1]);
    #pragma unroll
    for (int j = 0; j < 8; ++j) {
        int i = base + j;
        if (i < N) {
            rowptr[i] = run;
            cursor[i] = run;
            inv[i] = 1.0f / (float)max(v[j], 1);
            run += v[j];
        }
    }
    if ((int)blockIdx.x == (int)gridDim.x - 1 && t == 255) rowptr[N] = run;
}

__global__ void fill_csr_kernel(const int* __restrict__ src, const int* __restrict__ dst,
                                int* __restrict__ cursor, int* __restrict__ col, int E) {
    int e = blockIdx.x * 256 + threadIdx.x;
    if (e >= E) return;
    int pos = atomicAdd(&cursor[dst[e]], 1);
    col[pos] = src[e];
}

// ---- layer 1 fused: gather x-mean + MFMA (K=32) --------------------------
__global__ __launch_bounds__(256) void layer16_fused_kernel(
    const float* __restrict__ x, const int* __restrict__ rowptr,
    const int* __restrict__ col, const float* __restrict__ inv,
    const bf16_t* __restrict__ wbf1, const float* __restrict__ bias,
    bf16_t* __restrict__ hout, int n) {
    const int t = threadIdx.x;
    const int lane = t & 63;
    const int wave = t >> 6;
    const int r = lane & 15;
    const int q = lane >> 4;
    const int m0 = blockIdx.x * 64 + (wave >> 1) * 32;
    const int nb = (wave & 1) * 64;

    bf16x8 aF[2];
    #pragma unroll
    for (int mt = 0; mt < 2; ++mt) {
        int node = m0 + mt * 16 + r;
        if (node >= n) node = n - 1;
        float acc[8];
        if (q < 2) {
            #pragma unroll
            for (int j = 0; j < 8; ++j) acc[j] = 0.f;
            const int lo = rowptr[node], hi = rowptr[node + 1];
            int e = lo;
            for (; e + 1 < hi; e += 2) {
                int s0 = col[e], s1 = col[e + 1];
                float4 u0 = *(const float4*)&x[s0 * 16 + q * 8];
                float4 u1 = *(const float4*)&x[s0 * 16 + q * 8 + 4];
                float4 u2 = *(const float4*)&x[s1 * 16 + q * 8];
                float4 u3 = *(const float4*)&x[s1 * 16 + q * 8 + 4];
                acc[0] += u0.x + u2.x; acc[1] += u0.y + u2.y;
                acc[2] += u0.z + u2.z; acc[3] += u0.w + u2.w;
                acc[4] += u1.x + u3.x; acc[5] += u1.y + u3.y;
                acc[6] += u1.z + u3.z; acc[7] += u1.w + u3.w;
            }
            if (e < hi) {
                int s0 = col[e];
                float4 u0 = *(const float4*)&x[s0 * 16 + q * 8];
                float4 u1 = *(const float4*)&x[s0 * 16 + q * 8 + 4];
                acc[0] += u0.x; acc[1] += u0.y; acc[2] += u0.z; acc[3] += u0.w;
                acc[4] += u1.x; acc[5] += u1.y; acc[6] += u1.z; acc[7] += u1.w;
            }
            float iv = inv[node];
            #pragma unroll
            for (int j = 0; j < 8; ++j) acc[j] *= iv;
        } else {
            float4 u0 = *(const float4*)&x[node * 16 + (q - 2) * 8];
            float4 u1 = *(const float4*)&x[node * 16 + (q - 2) * 8 + 4];
            acc[0] = u0.x; acc[1] = u0.y; acc[2] = u0.z; acc[3] = u0.w;
            acc[4] = u1.x; acc[5] = u1.y; acc[6] = u1.z; acc[7] = u1.w;
        }
        #pragma unroll
        for (int j = 0; j < 8; ++j) aF[mt][j] = (short)f2bf(acc[j]);
    }

    #pragma unroll
    for (int nt = 0; nt < 4; ++nt) {
        const int cidx = nb + nt * 16 + r;
        bf16x8 bF = *(const bf16x8*)(wbf1 + (size_t)cidx * 32 + q * 8);
        f32x4 acc0 = {0.f, 0.f, 0.f, 0.f};
        f32x4 acc1 = {0.f, 0.f, 0.f, 0.f};
        acc0 = __builtin_amdgcn_mfma_f32_16x16x32_bf16(aF[0], bF, acc0, 0, 0, 0);
        acc1 = __builtin_amdgcn_mfma_f32_16x16x32_bf16(aF[1], bF, acc1, 0, 0, 0);
        float bo = bias[cidx];
        #pragma unroll
        for (int reg = 0; reg < 4; ++reg) {
            int row0 = m0 + q * 4 + reg;
            if (row0 < n)
                hout[(size_t)row0 * 128 + cidx] = f2bf(fmaxf(acc0[reg] + bo, 0.0f));
            int row1 = m0 + 16 + q * 4 + reg;
            if (row1 < n)
                hout[(size_t)row1 * 128 + cidx] = f2bf(fmaxf(acc1[reg] + bo, 0.0f));
        }
    }
}

// ---- high-occupancy coalesced mean aggregate (R8): 16 lanes/node, 16B/lane,
// unroll-4 -> 16 independent 256B row reads in flight per wave.
__global__ __launch_bounds__(256) void aggregate128_kernel(
    const bf16_t* __restrict__ h, const int* __restrict__ rowptr,
    const int* __restrict__ col, const float* __restrict__ inv,
    bf16_t* __restrict__ aggb, int N) {
    const int t = threadIdx.x;
    const int node = blockIdx.x * 16 + (t >> 4);
    const int li = t & 15;
    if (node >= N) return;
    const int lo = rowptr[node], hi = rowptr[node + 1];
    float acc[8];
    #pragma unroll
    for (int j = 0; j < 8; ++j) acc[j] = 0.0f;
    int e = lo;
    for (; e + 3 < hi; e += 4) {
        int s0 = col[e], s1 = col[e + 1], s2 = col[e + 2], s3 = col[e + 3];
        uint4 v0 = *(const uint4*)&h[(size_t)s0 * 128 + li * 8];
        uint4 v1 = *(const uint4*)&h[(size_t)s1 * 128 + li * 8];
        uint4 v2 = *(const uint4*)&h[(size_t)s2 * 128 + li * 8];
        uint4 v3 = *(const uint4*)&h[(size_t)s3 * 128 + li * 8];
        acc8(acc, v0);
        acc8(acc, v1);
        acc8(acc, v2);
        acc8(acc, v3);
    }
    for (; e < hi; ++e) {
        uint4 v0 = *(const uint4*)&h[(size_t)col[e] * 128 + li * 8];
        acc8(acc, v0);
    }
    const float iv = inv[node];
    uint4 pk;
    pk.x = (uint32)f2bf(acc[0] * iv) | ((uint32)f2bf(acc[1] * iv) << 16);
    pk.y = (uint32)f2bf(acc[2] * iv) | ((uint32)f2bf(acc[3] * iv) << 16);
    pk.z = (uint32)f2bf(acc[4] * iv) | ((uint32)f2bf(acc[5] * iv) << 16);
    pk.w = (uint32)f2bf(acc[6] * iv) | ((uint32)f2bf(acc[7] * iv) << 16);
    *(uint4*)&aggb[(size_t)node * 128 + li * 8] = pk;
}

// ---- layer 2: MFMA bf16 GEMM, K=256, fragments straight from global ------
__global__ __launch_bounds__(256) void layer128_mfma_kernel(
    const bf16_t* __restrict__ aggb, const bf16_t* __restrict__ hin,
    const bf16_t* __restrict__ wbf, const float* __restrict__ bias,
    bf16_t* __restrict__ hout, int n) {
    const int t = threadIdx.x;
    const int lane = t & 63;
    const int wave = t >> 6;
    const int r = lane & 15;
    const int q = lane >> 4;
    const int m0 = blockIdx.x * 64 + (wave >> 1) * 32;
    const int nb = (wave & 1) * 64;

    bf16x8 aF[2][8];
    #pragma unroll
    for (int mt = 0; mt < 2; ++mt) {
        int node = m0 + mt * 16 + r;
        if (node >= n) node = n - 1;
        const bf16_t* arow = aggb + (size_t)node * 128;
        const bf16_t* hrow = hin + (size_t)node * 128;
        #pragma unroll
        for (int ks = 0; ks < 4; ++ks)
            aF[mt][ks] = *(const bf16x8*)(arow + ks * 32 + q * 8);
        #pragma unroll
        for (int ks = 0; ks < 4; ++ks)
            aF[mt][4 + ks] = *(const bf16x8*)(hrow + ks * 32 + q * 8);
    }

    #pragma unroll
    for (int nt = 0; nt < 4; ++nt) {
        const int cidx = nb + nt * 16 + r;
        const bf16_t* wrow = wbf + (size_t)cidx * 256;
        f32x4 acc0 = {0.f, 0.f, 0.f, 0.f};
        f32x4 acc1 = {0.f, 0.f, 0.f, 0.f};
        #pragma unroll
        for (int ks = 0; ks < 8; ++ks) {
            bf16x8 bF = *(const bf16x8*)(wrow + ks * 32 + q * 8);
            acc0 = __builtin_amdgcn_mfma_f32_16x16x32_bf16(aF[0][ks], bF, acc0, 0, 0, 0);
            acc1 = __builtin_amdgcn_mfma_f32_16x16x32_bf16(aF[1][ks], bF, acc1, 0, 0, 0);
        }
        float bo = bias[cidx];
        #pragma unroll
        for (int reg = 0; reg < 4; ++reg) {
            int row0 = m0 + q * 4 + reg;
            if (row0 < n)
                hout[(size_t)row0 * 128 + cidx] = f2bf(fmaxf(acc0[reg] + bo, 0.0f));
            int row1 = m0 + 16 + q * 4 + reg;
            if (row1 < n)
                hout[(size_t)row1 * 128 + cidx] = f2bf(fmaxf(acc1[reg] + bo, 0.0f));
        }
    }
}

// ---- layer 3 + head fused via LDS tile (R8) ------------------------------
__global__ __launch_bounds__(256) void layer128_head_mfma_kernel(
    const bf16_t* __restrict__ aggb, const bf16_t* __restrict__ hin,
    const bf16_t* __restrict__ wbf, const float* __restrict__ bias,
    const float* __restrict__ Wh, const float* __restrict__ bh,
    float* __restrict__ out, int n) {
    __shared__ bf16_t hs[64][132];

    const int t = threadIdx.x;
    const int lane = t & 63;
    const int wave = t >> 6;
    const int r = lane & 15;
    const int q = lane >> 4;
    const int n0 = blockIdx.x * 64;
    const int m0 = n0 + (wave >> 1) * 32;
    const int nb = (wave & 1) * 64;

    bf16x8 aF[2][8];
    #pragma unroll
    for (int mt = 0; mt < 2; ++mt) {
        int node = m0 + mt * 16 + r;
        if (node >= n) node = n - 1;
        const bf16_t* arow = aggb + (size_t)node * 128;
        const bf16_t* hrow = hin + (size_t)node * 128;
        #pragma unroll
        for (int ks = 0; ks < 4; ++ks)
            aF[mt][ks] = *(const bf16x8*)(arow + ks * 32 + q * 8);
        #pragma unroll
        for (int ks = 0; ks < 4; ++ks)
            aF[mt][4 + ks] = *(const bf16x8*)(hrow + ks * 32 + q * 8);
    }

    const int mloc = (wave >> 1) * 32;
    #pragma unroll
    for (int nt = 0; nt < 4; ++nt) {
        const int cidx = nb + nt * 16 + r;
        const bf16_t* wrow = wbf + (size_t)cidx * 256;
        f32x4 acc0 = {0.f, 0.f, 0.f, 0.f};
        f32x4 acc1 = {0.f, 0.f, 0.f, 0.f};
        #pragma unroll
        for (int ks = 0; ks < 8; ++ks) {
            bf16x8 bF = *(const bf16x8*)(wrow + ks * 32 + q * 8);
            acc0 = __builtin_amdgcn_mfma_f32_16x16x32_bf16(aF[0][ks], bF, acc0, 0, 0, 0);
            acc1 = __builtin_amdgcn_mfma_f32_16x16x32_bf16(aF[1][ks], bF, acc1, 0, 0, 0);
        }
        float bo = bias[cidx];
        #pragma unroll
        for (int reg = 0; reg < 4; ++reg) {
            hs[mloc + q * 4 + reg][cidx]      = f2bf(fmaxf(acc0[reg] + bo, 0.0f));
            hs[mloc + 16 + q * 4 + reg][cidx] = f2bf(fmaxf(acc1[reg] + bo, 0.0f));
        }
    }
    __syncthreads();

    const int nl = t >> 2;
    const int o  = t & 3;
    const int node = n0 + nl;
    if (node >= n) return;
    const float* wr = Wh + o * 128;
    float acc = bh[o];
    #pragma unroll
    for (int kb = 0; kb < 16; ++kb) {
        bf16x8 hv = *(const bf16x8*)&hs[nl][kb * 8];
        float4 w0 = *(const float4*)&wr[kb * 8];
        float4 w1 = *(const float4*)&wr[kb * 8 + 4];
        acc = fmaf(bf2f((bf16_t)hv[0]), w0.x, acc);
        acc = fmaf(bf2f((bf16_t)hv[1]), w0.y, acc);
        acc = fmaf(bf2f((bf16_t)hv[2]), w0.z, acc);
        acc = fmaf(bf2f((bf16_t)hv[3]), w0.w, acc);
        acc = fmaf(bf2f((bf16_t)hv[4]), w1.x, acc);
        acc = fmaf(bf2f((bf16_t)hv[5]), w1.y, acc);
        acc = fmaf(bf2f((bf16_t)hv[6]), w1.z, acc);
        acc = fmaf(bf2f((bf16_t)hv[7]), w1.w, acc);
    }
    out[(size_t)node * 4 + o] = acc;
}

extern "C" void kernel_launch(void* const* d_in, const int* in_sizes, int n_in,
                              void* d_out, int out_size, void* d_ws, size_t ws_size,
                              hipStream_t stream) {
    const float* x   = (const float*)d_in[0];
    const int*   ei  = (const int*)d_in[1];
    const float* Wl1 = (const float*)d_in[2];
    const float* Wr1 = (const float*)d_in[3];
    const float* b1  = (const float*)d_in[4];
    const float* Wl2 = (const float*)d_in[5];
    const float* Wr2 = (const float*)d_in[6];
    const float* b2  = (const float*)d_in[7];
    const float* Wl3 = (const float*)d_in[8];
    const float* Wr3 = (const float*)d_in[9];
    const float* b3  = (const float*)d_in[10];
    const float* Wh  = (const float*)d_in[11];
    const float* bh  = (const float*)d_in[12];
    float* out = (float*)d_out;

    const int N = in_sizes[0] / 16;
    const int E = in_sizes[1] / 2;
    const int* src = ei;
    const int* dst = ei + E;

    const int nScanBlocks = (N + SCAN_CHUNK - 1) / SCAN_CHUNK;
    const int nZero = (N + 255) >> 8;

    int* deg       = (int*)d_ws;                       // N
    int* rowptr    = deg + N;                          // N+1 (pad 8)
    int* cursor    = rowptr + (N + 8);                 // N
    int* blocksum  = cursor + N;                       // pad 64
    int* col       = blocksum + 64;                    // E
    float* inv     = (float*)(col + E);                // N
    bf16_t* aggb   = (bf16_t*)(inv + N);               // N*128 bf16
    bf16_t* hA     = aggb + (size_t)N * 128;           // N*128 bf16
    bf16_t* hB     = hA + (size_t)N * 128;             // N*128 bf16
    bf16_t* wbf1   = hB + (size_t)N * 128;             // 128*32 bf16
    bf16_t* wbf2   = wbf1 + 128 * 32;                  // 128*256 bf16
    bf16_t* wbf3   = wbf2 + 128 * 256;                 // 128*256 bf16

    const int B = 256;
    auto blocks = [](long total, int b) { return (int)((total + b - 1) / b); };

    // ---- setup + CSR build (5 dispatches) ----
    prep_kernel<<<nZero + 272, B, 0, stream>>>(deg, N, Wl1, Wr1, wbf1,
                                               Wl2, Wr2, wbf2, Wl3, Wr3, wbf3);
    count_deg_kernel<<<blocks(E, B), B, 0, stream>>>(dst, deg, E);
    scan_partial_kernel<<<nScanBlocks, B, 0, stream>>>(deg, blocksum, N);
    scan_final_kernel<<<nScanBlocks, B, 0, stream>>>(deg, blocksum, rowptr, cursor, inv, N);
    fill_csr_kernel<<<blocks(E, B), B, 0, stream>>>(src, dst, cursor, col, E);

    // ---- layer 1: fused x-gather + MFMA (K=32) ----
    layer16_fused_kernel<<<blocks(N, 64), B, 0, stream>>>(
        x, rowptr, col, inv, wbf1, b1, hA, N);

    // ---- layer 2: aggregate + MFMA GEMM ----
    aggregate128_kernel<<<blocks(N, 16), B, 0, stream>>>(hA, rowptr, col, inv, aggb, N);
    layer128_mfma_kernel<<<blocks(N, 64), B, 0, stream>>>(aggb, hA, wbf2, b2, hB, N);

    // ---- layer 3 + head fused ----
    aggregate128_kernel<<<blocks(N, 16), B, 0, stream>>>(hB, rowptr, col, inv, aggb, N);
    layer128_head_mfma_kernel<<<blocks(N, 64), B, 0, stream>>>(
        aggb, hB, wbf3, b3, Wh, bh, out, N);
}